// Round 5
// baseline (938.297 us; speedup 1.0000x reference)
//
#include <hip/hip_runtime.h>
#include <hip/hip_bf16.h>
#include <stdint.h>

// NNUE bucket model R5: BARRIER-FREE K-loops.
// R4 lesson (== m99/m100): per-iter __syncthreads drains vmcnt(0) including
// prefetches -> dbuf can't work. New structure: B-slice resident in LDS
// (staged in 52 KB chunks, 2-3 stages => 3 blocks/CU), A streamed directly
// global->VGPR in MFMA fragment layout with depth-3 circular prefetch,
// ZERO barriers in the K-loop (3 total per block vs 25).
//   K1: convert_x: fp32 -> fp16 (2B,800) zero-padded + fp32 pc/bucket (vectorized)
//   K2: convert_w: ft_w -> (512,800) fp16 padded, h1_w -> (256,1024) fp16
//   K3: gemm_ft: M=256 N=64 per block (4 waves, wave 64x64), K=800, fan-8,
//       XCD-grouped so an mt's 8 n-blocks share one XCD's L2.
//   K4: gemm_h1: M=256 N=64, K=1024 (A = concat trick), fan-4.
//   K5: tail unchanged.
// LDS chunk-XOR swizzle (R2-verified: 0 conflicts); gl_lds dst strictly
// lane-linear (swizzle applied on SOURCE index).

#define INF  770
#define XROW 1540
#define KP   800
#define FT   512
#define K2   1024
#define N2   256

typedef _Float16 half8 __attribute__((ext_vector_type(8)));
typedef _Float16 half4 __attribute__((ext_vector_type(4)));
typedef float floatx4 __attribute__((ext_vector_type(4)));
typedef float floatx2 __attribute__((ext_vector_type(2)));

__device__ __forceinline__ float crelu_f(float v) {
    return v < 0.f ? 0.f : (v > 1.f ? 1.f : v);
}

__device__ __forceinline__ void gl_lds16(const _Float16* g, _Float16* l) {
    __builtin_amdgcn_global_load_lds(
        (__attribute__((address_space(1))) void*)(uintptr_t)(const void*)g,
        (__attribute__((address_space(3))) void*)l,
        16, 0, 0);
}

// ---------------- K1: convert x + bucket (vectorized) ----------------
__global__ __launch_bounds__(256) void convert_x_kernel(
    const float* __restrict__ x, _Float16* __restrict__ x16,
    int* __restrict__ bucket, int B)
{
    __shared__ float red[4];
    int b = blockIdx.x;
    int tid = threadIdx.x, lane = tid & 63, w = tid >> 6;
    const float* src = x + (size_t)b * XROW;
    float s = 0.f;
    if (tid < 200) {
        int i0 = tid * 4;
        half4 v0, v1;
        if (tid < 192) {
            floatx4 f = *(const floatx4*)(src + i0);          // 16B aligned
            v0[0] = (_Float16)f.x; v0[1] = (_Float16)f.y;
            v0[2] = (_Float16)f.z; v0[3] = (_Float16)f.w;
            s = (f.x + f.y) + (f.z + f.w);                     // i0..i0+3 < 768
            floatx2 g0 = *(const floatx2*)(src + 770 + i0);    // 8B aligned
            floatx2 g1 = *(const floatx2*)(src + 772 + i0);
            v1[0] = (_Float16)g0.x; v1[1] = (_Float16)g0.y;
            v1[2] = (_Float16)g1.x; v1[3] = (_Float16)g1.y;
        } else if (tid == 192) {
            floatx2 f = *(const floatx2*)(src + 768);          // 768,769 real
            v0[0] = (_Float16)f.x; v0[1] = (_Float16)f.y; v0[2] = 0; v0[3] = 0;
            floatx2 g = *(const floatx2*)(src + 1538);         // 1538,1539 real
            v1[0] = (_Float16)g.x; v1[1] = (_Float16)g.y; v1[2] = 0; v1[3] = 0;
        } else {
            v0 = half4{0, 0, 0, 0}; v1 = half4{0, 0, 0, 0};
        }
        *(half4*)(x16 + (size_t)b * KP + i0) = v0;
        *(half4*)(x16 + ((size_t)B + b) * KP + i0) = v1;
    }
    #pragma unroll
    for (int off = 32; off; off >>= 1) s += __shfl_down(s, off, 64);
    if (lane == 0) red[w] = s;
    __syncthreads();
    if (tid == 0) {
        float pc = red[0] + red[1] + red[2] + red[3];
        int bk = (int)((pc * 8.0f) / 33.0f);                   // mirror reference
        bucket[b] = bk < 0 ? 0 : (bk > 7 ? 7 : bk);
    }
}

// ---------------- K2: convert weights ----------------
__global__ __launch_bounds__(256) void convert_w_kernel(
    const float* __restrict__ ftw, const float* __restrict__ h1w,
    _Float16* __restrict__ ftw16, _Float16* __restrict__ h1w16)
{
    int idx = blockIdx.x * 256 + threadIdx.x;
    const int FTW = FT * KP;            // 409600
    if (idx < FTW) {
        int r = idx / KP, c = idx - r * KP;
        ftw16[idx] = (_Float16)(c < INF ? ftw[r * INF + c] : 0.f);
    } else {
        int j = idx - FTW;
        if (j < N2 * K2) h1w16[j] = (_Float16)h1w[j];
    }
}

// ---------------- K3: FT GEMM, barrier-free K-loop ----------------
// Block: 256 thr / 4 waves; tile M=256 (wave m-slices of 64) x N=64; K=800.
// LDS: B-slice 64 rows x 13 kt-blocks (52 KB), restaged once (kt>=13).
__global__ __launch_bounds__(256) void gemm_ft(
    const _Float16* __restrict__ A,   // (2B, 800) x16, zero-padded
    const _Float16* __restrict__ Bt,  // (512, 800) padded fp16
    const float* __restrict__ bias,   // (512)
    _Float16* __restrict__ C)         // (2B, 512)
{
    __shared__ _Float16 lsB[13 * 64 * 32];   // 53248 B
    int bid = blockIdx.x;
    // XCD grouping (assume xcd = bid&7): XCD c runs k=bid>>3 in order;
    // mt = c*64 + (k>>3), nt = k&7 -> an mt's 8 n-blocks are 8 consecutive k
    // on ONE XCD (A-slice 400 KB stays in its L2).
    int xcd = bid & 7, kk = bid >> 3;
    int mt = xcd * 64 + (kk >> 3), nt = kk & 7;
    int m0 = mt * 256, n0 = nt * 64;
    int tid = threadIdx.x, lane = tid & 63, w = tid >> 6;
    int colL = lane & 15, rowQ = lane >> 4;
    int chA = rowQ ^ ((colL >> 1) & 3);
    int mw = m0 + w * 64;

    const _Float16* a0 = A + (size_t)(mw + colL) * KP + rowQ * 8;

    floatx4 acc[4][4] = {};
    half8 apf[3][4];

    // stage 1: kt-blocks 0..12 (swizzle on SOURCE chunk; LDS dst lane-linear)
    for (int t = tid; t < 13 * 256; t += 256) {
        int ktb = t >> 8, r = t & 255, n = r >> 2, kq = r & 3;
        int srcq = kq ^ ((n >> 1) & 3);
        gl_lds16(Bt + (size_t)(n0 + n) * KP + ktb * 32 + srcq * 8, lsB + t * 8);
    }
    // A prefetch: kt = 0,1,2
    #pragma unroll
    for (int d = 0; d < 3; ++d)
        #pragma unroll
        for (int i = 0; i < 4; ++i)
            apf[d][i] = *(const half8*)(a0 + (size_t)i * 16 * KP + d * 32);
    asm volatile("s_waitcnt vmcnt(0)" ::: "memory");
    __syncthreads();

    #pragma unroll
    for (int kt = 0; kt < 25; ++kt) {
        if (kt == 13) {
            __syncthreads();                 // stage-1 reads complete
            for (int t = tid; t < 12 * 256; t += 256) {
                int ktb = t >> 8, r = t & 255, n = r >> 2, kq = r & 3;
                int srcq = kq ^ ((n >> 1) & 3);
                gl_lds16(Bt + (size_t)(n0 + n) * KP + (13 + ktb) * 32 + srcq * 8,
                         lsB + t * 8);
            }
            asm volatile("s_waitcnt vmcnt(0)" ::: "memory");
            __syncthreads();
        }
        int ktRel = (kt < 13) ? kt : kt - 13;
        half8 bf[4], af[4];
        #pragma unroll
        for (int j = 0; j < 4; ++j)
            bf[j] = *(const half8*)(lsB + ktRel * 2048 + (j * 16 + colL) * 32 + chA * 8);
        #pragma unroll
        for (int i = 0; i < 4; ++i) af[i] = apf[kt % 3][i];
        if (kt + 3 < 25) {
            #pragma unroll
            for (int i = 0; i < 4; ++i)
                apf[kt % 3][i] = *(const half8*)(a0 + (size_t)i * 16 * KP + (kt + 3) * 32);
        }
        #pragma unroll
        for (int i = 0; i < 4; ++i)
            #pragma unroll
            for (int j = 0; j < 4; ++j)
                acc[i][j] = __builtin_amdgcn_mfma_f32_16x16x32_f16(af[i], bf[j], acc[i][j], 0, 0, 0);
    }

    #pragma unroll
    for (int j = 0; j < 4; ++j) {
        int gn = n0 + j * 16 + colL;
        float bv = bias[gn];
        #pragma unroll
        for (int i = 0; i < 4; ++i)
            #pragma unroll
            for (int r = 0; r < 4; ++r) {
                int gm = mw + i * 16 + rowQ * 4 + r;
                C[(size_t)gm * FT + gn] = (_Float16)crelu_f(acc[i][j][r] + bv);
            }
    }
}

// ---------------- K4: h1 GEMM, barrier-free K-loop ----------------
// Block: 256 thr / 4 waves; M=256 x N=64; K=1024 (A = [C1[m] | C1[B+m]]).
// LDS: 64 rows x 13 kt-blocks, stages 13/13/6.
__global__ __launch_bounds__(256) void gemm_h1(
    const _Float16* __restrict__ C1,  // (2B, 512)
    const _Float16* __restrict__ Bt,  // (256, 1024)
    const float* __restrict__ bias,   // (256)
    float* __restrict__ H,            // (B, 256)
    int B)
{
    __shared__ _Float16 lsB[13 * 64 * 32];
    int bid = blockIdx.x;
    int xcd = bid & 7, kk = bid >> 3;
    int mt = xcd * 32 + (kk >> 2), nt = kk & 3;
    int m0 = mt * 256, n0 = nt * 64;
    int tid = threadIdx.x, lane = tid & 63, w = tid >> 6;
    int colL = lane & 15, rowQ = lane >> 4;
    int chA = rowQ ^ ((colL >> 1) & 3);
    int mw = m0 + w * 64;

    const _Float16* a0lo = C1 + (size_t)(mw + colL) * FT + rowQ * 8;
    const _Float16* a0hi = C1 + (size_t)(B + mw + colL) * FT + rowQ * 8;

    floatx4 acc[4][4] = {};
    half8 apf[3][4];

    #define H1_AFRAG(KT, I) \
        (*(const half8*)(((KT) < 16 ? a0lo + (KT) * 32 : a0hi + ((KT) - 16) * 32) \
                         + (size_t)(I) * 16 * FT))
    #define H1_STAGE(KT0, NKT) do {                                             \
        for (int t = tid; t < (NKT) * 256; t += 256) {                          \
            int ktb = t >> 8, r = t & 255, n = r >> 2, kq = r & 3;              \
            int srcq = kq ^ ((n >> 1) & 3);                                     \
            gl_lds16(Bt + (size_t)(n0 + n) * K2 + ((KT0) + ktb) * 32 + srcq * 8,\
                     lsB + t * 8);                                              \
        }                                                                       \
    } while (0)

    H1_STAGE(0, 13);
    #pragma unroll
    for (int d = 0; d < 3; ++d)
        #pragma unroll
        for (int i = 0; i < 4; ++i)
            apf[d][i] = H1_AFRAG(d, i);
    asm volatile("s_waitcnt vmcnt(0)" ::: "memory");
    __syncthreads();

    #pragma unroll
    for (int kt = 0; kt < 32; ++kt) {
        if (kt == 13 || kt == 26) {
            __syncthreads();
            if (kt == 13) H1_STAGE(13, 13); else H1_STAGE(26, 6);
            asm volatile("s_waitcnt vmcnt(0)" ::: "memory");
            __syncthreads();
        }
        int ktRel = (kt < 13) ? kt : (kt < 26 ? kt - 13 : kt - 26);
        half8 bf[4], af[4];
        #pragma unroll
        for (int j = 0; j < 4; ++j)
            bf[j] = *(const half8*)(lsB + ktRel * 2048 + (j * 16 + colL) * 32 + chA * 8);
        #pragma unroll
        for (int i = 0; i < 4; ++i) af[i] = apf[kt % 3][i];
        if (kt + 3 < 32) {
            #pragma unroll
            for (int i = 0; i < 4; ++i)
                apf[kt % 3][i] = H1_AFRAG(kt + 3, i);
        }
        #pragma unroll
        for (int i = 0; i < 4; ++i)
            #pragma unroll
            for (int j = 0; j < 4; ++j)
                acc[i][j] = __builtin_amdgcn_mfma_f32_16x16x32_f16(af[i], bf[j], acc[i][j], 0, 0, 0);
    }
    #undef H1_AFRAG
    #undef H1_STAGE

    #pragma unroll
    for (int j = 0; j < 4; ++j) {
        int gn = n0 + j * 16 + colL;
        float bv = bias[gn];
        #pragma unroll
        for (int i = 0; i < 4; ++i)
            #pragma unroll
            for (int r = 0; r < 4; ++r) {
                int gm = mw + i * 16 + rowQ * 4 + r;
                H[(size_t)gm * N2 + gn] = crelu_f(acc[i][j][r] + bv);
            }
    }
}

// ---------------- K5: tail (h2 + h3, bucket-selected) ----------------
__global__ __launch_bounds__(256) void tail_kernel(
    const float* __restrict__ H,
    const int* __restrict__ bucket,
    const float* __restrict__ h2w,     // (8,32,32)
    const float* __restrict__ h2b,     // (8,32)
    const float* __restrict__ h3w,     // (8,1,32)
    const float* __restrict__ h3b,     // (8,1)
    float* __restrict__ out, int B)
{
    int s = blockIdx.x * 8 + (threadIdx.x >> 5);
    int j = threadIdx.x & 31;
    if (s >= B) return;
    int k = bucket[s];
    float h1v = H[(size_t)s * N2 + k * 32 + j];
    const float* w2 = h2w + ((k * 32 + j) * 32);
    float a = h2b[k * 32 + j];
    #pragma unroll
    for (int i = 0; i < 32; ++i) a += w2[i] * __shfl(h1v, i, 32);
    a = crelu_f(a);
    float p = a * h3w[k * 32 + j];
    #pragma unroll
    for (int off = 16; off; off >>= 1) p += __shfl_down(p, off, 32);
    if (j == 0) out[s] = p + h3b[k];
}

extern "C" void kernel_launch(void* const* d_in, const int* in_sizes, int n_in,
                              void* d_out, int out_size, void* d_ws, size_t ws_size,
                              hipStream_t stream) {
    const float* x    = (const float*)d_in[0];
    const float* ftw  = (const float*)d_in[1];
    const float* ftb  = (const float*)d_in[2];
    const float* h1w  = (const float*)d_in[3];
    const float* h1b  = (const float*)d_in[4];
    const float* h2w  = (const float*)d_in[5];
    const float* h2b  = (const float*)d_in[6];
    const float* h3w  = (const float*)d_in[7];
    const float* h3b  = (const float*)d_in[8];
    float* out = (float*)d_out;

    int B = in_sizes[0] / (2 * INF);          // 65536

    // workspace layout
    char* ws = (char*)d_ws;
    _Float16* x16   = (_Float16*)ws;                          // 2B*800*2 = 210 MB
    size_t x16_b    = (size_t)2 * B * KP * sizeof(_Float16);
    _Float16* C1    = (_Float16*)(ws + x16_b);                // 2B*512*2 = 134 MB
    size_t c1_b     = (size_t)2 * B * FT * sizeof(_Float16);
    _Float16* ftw16 = (_Float16*)(ws + x16_b + c1_b);         // 512*800*2
    size_t ftw_b    = (size_t)FT * KP * sizeof(_Float16);
    _Float16* h1w16 = (_Float16*)(ws + x16_b + c1_b + ftw_b); // 256*1024*2
    size_t h1w_b    = (size_t)N2 * K2 * sizeof(_Float16);
    int* bucket     = (int*)(ws + x16_b + c1_b + ftw_b + h1w_b); // B*4
    float* H        = (float*)ws;   // alias x16 (dead after gemm_ft): B*256*4

    // K2: weights
    {
        int total = FT * KP + N2 * K2;
        convert_w_kernel<<<(total + 255) / 256, 256, 0, stream>>>(ftw, h1w, ftw16, h1w16);
    }
    // K1: x conversion + bucket
    convert_x_kernel<<<B, 256, 0, stream>>>(x, x16, bucket, B);
    // K3: FT GEMM  (grid = 512 mt x 8 nt = 4096)
    gemm_ft<<<4096, 256, 0, stream>>>(x16, ftw16, ftb, C1);
    // K4: h1 GEMM (grid = 256 mt x 4 nt = 1024)
    gemm_h1<<<1024, 256, 0, stream>>>(C1, h1w16, h1b, H, B);
    // K5: tail
    tail_kernel<<<(B + 7) / 8, 256, 0, stream>>>(H, bucket, h2w, h2b, h3w, h3b, out, B);
}